// Round 6
// baseline (195.478 us; speedup 1.0000x reference)
//
#include <hip/hip_runtime.h>

typedef unsigned short u16;
typedef unsigned int u32;
typedef __attribute__((ext_vector_type(8))) short bf16x8;
typedef __attribute__((ext_vector_type(4))) float f32x4;

#define B_   128
#define P_   2048
#define NC_  10
#define F_   160      // NC*CLO
#define NBLK 512      // k_pass blocks: 2 per CU (proven best occupancy)
#define PPB  4        // p-tiles per block
#define NTHR 512

__device__ __forceinline__ u16 f2bf(float f) {
    union { float f; unsigned u; } v; v.f = f;
    unsigned r = v.u + 0x7FFFu + ((v.u >> 16) & 1u);   // RNE
    return (u16)(r >> 16);
}
__device__ __forceinline__ float bf2f(u16 h) {
    union { unsigned u; float f; } v; v.u = ((unsigned)h) << 16;
    return v.f;
}

// Fused prep (hardware-validated; SQ_LDS_BANK_CONFLICT=0 downstream).
// Blocks 0..4095: squash along NP=32, bf16-cast, write xb[p][b][chunk] with
// chunk XOR-swizzle (slot' = slot ^ ((b>>1)&3)). Blocks 4096..6143:
// weight[p][k][f] fp32 -> wb[p][f][k] bf16 transpose via LDS, same swizzle.
__global__ void k_prep(const float* __restrict__ t, const float* __restrict__ w,
                       u16* __restrict__ xb, u16* __restrict__ wb) {
    __shared__ u16 wl[32 * F_];
    const int tid = threadIdx.x;
    if (blockIdx.x < 4096) {
        int g = blockIdx.x * 256 + tid;
        int pair = g >> 2, sub = g & 3;
        int p = pair & 2047, b = pair >> 11;
        const float4* tg = (const float4*)t;
        int fi = pair * 8 + sub * 2;
        float4 va = tg[fi], vb = tg[fi + 1];
        float ss = va.x*va.x + va.y*va.y + va.z*va.z + va.w*va.w
                 + vb.x*vb.x + vb.y*vb.y + vb.z*vb.z + vb.w*vb.w;
        ss += __shfl_xor(ss, 1);      // quad holds the full 32-elem sum
        ss += __shfl_xor(ss, 2);
        float fct = ss / ((1.f + ss) * sqrtf(ss));
        u16 h[8] __attribute__((aligned(16)));
        h[0]=f2bf(va.x*fct); h[1]=f2bf(va.y*fct); h[2]=f2bf(va.z*fct); h[3]=f2bf(va.w*fct);
        h[4]=f2bf(vb.x*fct); h[5]=f2bf(vb.y*fct); h[6]=f2bf(vb.z*fct); h[7]=f2bf(vb.w*fct);
        int sw = sub ^ ((b >> 1) & 3);
        *(uint4*)(xb + (p * 128 + b) * 32 + sw * 8) = *(const uint4*)h;
    } else {
        int p = blockIdx.x - 4096;
        const float4* wp = (const float4*)(w + p * 32 * F_);
        for (int e4 = tid; e4 < 1280; e4 += 256) {
            float4 v = wp[e4];
            u16 h[4] __attribute__((aligned(8)));
            h[0]=f2bf(v.x); h[1]=f2bf(v.y); h[2]=f2bf(v.z); h[3]=f2bf(v.w);
            *(ushort4*)(wl + e4 * 4) = *(const ushort4*)h;
        }
        __syncthreads();
        u16* wo = wb + p * F_ * 32;
        for (int sid = tid; sid < 640; sid += 256) {
            int f = sid >> 2, k0 = (sid & 3) << 3;
            u16 tmp[8] __attribute__((aligned(16)));
#pragma unroll
            for (int j = 0; j < 8; ++j) tmp[j] = wl[(k0 + j) * F_ + f];
            int sw = (sid & 3) ^ ((f >> 1) & 3);
            *(uint4*)(wo + f * 32 + sw * 8) = *(const uint4*)tmp;
        }
    }
}

// One routing pass -- R4 skeleton (reg-staged double-buffered LDS, two
// barriers per tile, 2 blocks/CU, 128-VGPR budget). CHANGE vs R4: in
// MODE>=1, u[n] from the first MFMA pass is KEPT IN REGISTERS and reused
// for the weighted sum (no second MFMA pass, no second afrag ds_read).
// Register headroom comes from demoting vv: instead of 40 always-live
// VGPRs, v is reloaded per tile from global (80 KB, L2/LLC-hot, coalesced
// 1KB/wave-instr). DS-pipe work per wave-tile drops ~2x -- the theory is
// that k_pass is LDS-throughput-bound, not staging/barrier-bound.
template<int MODE>
__global__ __launch_bounds__(NTHR, 2) void k_pass(
        const u16* __restrict__ xb, const u16* __restrict__ wb,
        const float* __restrict__ vprev, u16* __restrict__ s_part)
{
    __shared__ u16 xt[2][4096];    // 2 x 8 KB
    __shared__ u16 wt[2][5120];    // 2 x 10 KB
    const int tid = threadIdx.x, blk = blockIdx.x;
    const int L = tid & 63, wv = tid >> 6;
    const int q = L >> 4, col = L & 15;
    const int b = wv * 16 + col;
    const int qs = (q ^ ((col >> 1) & 3)) * 8;   // swizzled k-slot (shorts)
    const int p0 = blk * PPB;

    // per-thread base into vprev (loop-invariant address math only)
    const float* vp = (MODE != 0) ? (vprev + b * F_ + q * 4) : nullptr;

    f32x4 s_acc[NC_];
#pragma unroll
    for (int n = 0; n < NC_; ++n) s_acc[n] = (f32x4){0.f, 0.f, 0.f, 0.f};

    // prefetch registers: x tile = 512 uint4, w tile = 640 uint4
    uint4 r0, r1, r2;
    {
        const uint4* xg = (const uint4*)(xb + (size_t)p0 * 4096);
        const uint4* wg = (const uint4*)(wb + (size_t)p0 * 5120);
        r0 = xg[tid]; r1 = wg[tid];
        if (tid < 128) r2 = wg[tid + 512];
    }

    int cur = 0;
#pragma unroll
    for (int pp = 0; pp < PPB; ++pp) {
        __syncthreads();          // previous tile fully consumed
        ((uint4*)xt[cur])[tid] = r0;
        ((uint4*)wt[cur])[tid] = r1;
        if (tid < 128) ((uint4*)wt[cur])[512 + tid] = r2;
        if (pp + 1 < PPB) {       // next tile's loads fly during compute
            const uint4* xg = (const uint4*)(xb + (size_t)(p0 + pp + 1) * 4096);
            const uint4* wg = (const uint4*)(wb + (size_t)(p0 + pp + 1) * 5120);
            r0 = xg[tid]; r1 = wg[tid];
            if (tid < 128) r2 = wg[tid + 512];
        }
        __syncthreads();          // tile visible

        bf16x8 bfrag = *(const bf16x8*)&xt[cur][b * 32 + qs];   // x[b][k=q*8+j]
        if (MODE == 0) {
#pragma unroll
            for (int n = 0; n < NC_; ++n) {
                bf16x8 afrag = *(const bf16x8*)&wt[cur][(n * 16 + col) * 32 + qs];
                s_acc[n] = __builtin_amdgcn_mfma_f32_16x16x32_bf16(afrag, bfrag, s_acc[n], 0, 0, 0);
            }
        } else {
            // ---- u computed ONCE, kept in regs (10 MFMA, 11 ds_read_b128)
            f32x4 u[NC_];
#pragma unroll
            for (int n = 0; n < NC_; ++n) {
                bf16x8 afrag = *(const bf16x8*)&wt[cur][(n * 16 + col) * 32 + qs];
                f32x4 z = {0.f, 0.f, 0.f, 0.f};
                u[n] = __builtin_amdgcn_mfma_f32_16x16x32_bf16(afrag, bfrag, z, 0, 0, 0);
            }
            // ---- logits: t = u . v  (v reloaded per tile, transient regs)
            float tt[NC_];
#pragma unroll
            for (int n = 0; n < NC_; ++n) {
                float4 vvn = *(const float4*)(vp + n * 16);
                float tv = u[n][0]*vvn.x + u[n][1]*vvn.y + u[n][2]*vvn.z + u[n][3]*vvn.w;
                tv += __shfl_xor(tv, 16);   // full 16-elem dot over k'
                tv += __shfl_xor(tv, 32);
                tt[n] = tv;
            }
            float mx = tt[0];
#pragma unroll
            for (int n = 1; n < NC_; ++n) mx = fmaxf(mx, tt[n]);
            float den = 0.f;
#pragma unroll
            for (int n = 0; n < NC_; ++n) { tt[n] = __expf(tt[n] - mx); den += tt[n]; }
            float inv = 1.f / den;
#pragma unroll
            for (int n = 0; n < NC_; ++n) {
                float cf = tt[n] * inv;
#pragma unroll
                for (int r = 0; r < 4; ++r) s_acc[n][r] += cf * u[n][r];
            }
        }
        cur ^= 1;
    }

    // n-major partial store: per n, each wave writes 512 contiguous bytes
    // (4 full 128B lines) -> no partial-line RMW.
    u16* sp = s_part + blk * (B_ * F_);
    const float sc = (MODE == 0) ? 0.1f : 1.f;
#pragma unroll
    for (int n = 0; n < NC_; ++n) {
        u16 h[4] __attribute__((aligned(8)));
#pragma unroll
        for (int r = 0; r < 4; ++r) h[r] = f2bf(s_acc[n][r] * sc);
        *(ushort4*)(sp + n * 2048 + b * 16 + q * 4) = *(const ushort4*)h;
    }
}

// Sum bf16 partials over NBLK groups (n-major layout, uint4 = 8 bf16 per
// load), squash along CLO=16. ADD: add vprev (v0+v1 for next pass's logits).
template<int ADD>
__global__ void k_red(const u16* __restrict__ s_part,
                      const float* __restrict__ vprev, float* __restrict__ vout) {
    __shared__ float red[32 * 66];
    const int tid = threadIdx.x, blk = blockIdx.x;
    const int pid = tid & 7, part = tid >> 3;     // 8 uint4 lanes x 32 parts
    const uint4* sp4 = (const uint4*)s_part;      // 2560 uint4 per group
    const int base = blk * 8 + pid;               // uint4 column 0..2559
    float a[8];
#pragma unroll
    for (int j = 0; j < 8; ++j) a[j] = 0.f;
    for (int g = part; g < NBLK; g += 32) {       // 16 iterations
        uint4 uv = sp4[(size_t)g * 2560 + base];
        a[0] += bf2f((u16)(uv.x & 0xffff)); a[1] += bf2f((u16)(uv.x >> 16));
        a[2] += bf2f((u16)(uv.y & 0xffff)); a[3] += bf2f((u16)(uv.y >> 16));
        a[4] += bf2f((u16)(uv.z & 0xffff)); a[5] += bf2f((u16)(uv.z >> 16));
        a[6] += bf2f((u16)(uv.w & 0xffff)); a[7] += bf2f((u16)(uv.w >> 16));
    }
#pragma unroll
    for (int j = 0; j < 8; ++j) red[part * 66 + pid * 8 + j] = a[j];
    __syncthreads();
    if (tid < 32) {
        float s0 = 0.f, s1 = 0.f;
#pragma unroll
        for (int k = 0; k < 32; ++k) {
            s0 += red[k * 66 + tid * 2];
            s1 += red[k * 66 + tid * 2 + 1];
        }
        float sq = s0 * s0 + s1 * s1;
        sq += __shfl_xor(sq, 1);    // 8 lanes = 16 elems of one (b,n) row
        sq += __shfl_xor(sq, 2);
        sq += __shfl_xor(sq, 4);
        float fct = sq / ((1.f + sq) * sqrtf(sq));
        // remap n-major partial column -> b-major output offset
        const int i = blk * 8 + (tid >> 2);        // uint4 column of this pair
        const int n = i >> 8, bb = (i & 255) >> 1, hh = i & 1;
        const int f0 = bb * 160 + n * 16 + hh * 8 + 2 * (tid & 3);
        float2 o = make_float2(s0 * fct, s1 * fct);
        if (ADD) {
            float2 pv = *(const float2*)(vprev + f0);
            o.x += pv.x; o.y += pv.y;
        }
        *(float2*)(vout + f0) = o;
    }
}

extern "C" void kernel_launch(void* const* d_in, const int* in_sizes, int n_in,
                              void* d_out, int out_size, void* d_ws, size_t ws_size,
                              hipStream_t stream) {
    const float* tensor = (const float*)d_in[0];
    const float* weight = (const float*)d_in[1];
    float* out = (float*)d_out;
    char* ws = (char*)d_ws;

    u16*   xb     = (u16*)(ws);                       // 16,777,216 B
    u16*   wb     = (u16*)(ws + 16777216);            // 20,971,520 B
    u16*   s_part = (u16*)(ws + 37748736);            // 512*40960 B = 20,971,520 B
    float* v0     = (float*)(ws + 58720256);          // 81,920 B
    float* vs     = (float*)(ws + 58802176);          // 81,920 B (v0 + v1)

    k_prep<<<6144, 256, 0, stream>>>(tensor, weight, xb, wb);

    k_pass<0><<<NBLK, NTHR, 0, stream>>>(xb, wb, nullptr, s_part);
    k_red<0><<<320, 256, 0, stream>>>(s_part, nullptr, v0);
    k_pass<1><<<NBLK, NTHR, 0, stream>>>(xb, wb, v0, s_part);
    k_red<1><<<320, 256, 0, stream>>>(s_part, v0, vs);
    k_pass<2><<<NBLK, NTHR, 0, stream>>>(xb, wb, vs, s_part);
    k_red<0><<<320, 256, 0, stream>>>(s_part, nullptr, out);
}